// Round 4
// baseline (238.906 us; speedup 1.0000x reference)
//
#include <hip/hip_runtime.h>
#include <hip/hip_bf16.h>

typedef __attribute__((ext_vector_type(8))) short bf16x8;
typedef __attribute__((ext_vector_type(4))) float f32x4;

constexpr int BQ  = 4096;          // batch per view
constexpr int DD  = 128;           // dim
constexpr int N2  = 2 * BQ;        // 8192
constexpr int NCHK = 8;            // column chunks (1024 cols each)
constexpr int NCT  = 8;            // 128-col tiles per chunk
// exp(s/T) = exp2(s * 2/ln2); pre-scale matrix by sqrt(2.8853900817779268)
constexpr float SQS = 1.6986433f;

static __device__ __forceinline__ ushort f2bf(float f) {
    unsigned u = __builtin_bit_cast(unsigned, f);
    u += 0x7FFFu + ((u >> 16) & 1u);     // round-to-nearest-even
    return (ushort)(u >> 16);
}

static __device__ __forceinline__ void gll(const void* g, void* l) {
    __builtin_amdgcn_global_load_lds(
        (const __attribute__((address_space(1))) void*)g,
        (__attribute__((address_space(3))) void*)l, 16, 0, 0);
}

// ---- kernel 1: fp32 -> bf16 in MFMA-fragment order, plus mask keys --------
// obF layout: frag(group,kk) at index (group*4+kk)*64+lane, 8 bf16 per lane:
// a fragment load is F[base+lane] -> one fully contiguous 1KB load per wave.
__global__ __launch_bounds__(256) void convert_k(const float* __restrict__ a,
        const float* __restrict__ b, const int* __restrict__ tgt,
        ushort* __restrict__ obF, int* __restrict__ key)
{
    int t = blockIdx.x * 256 + threadIdx.x;          // 131072 threads
    int row = t >> 4, c8 = t & 15;
    const float* src = (row < BQ) ? (a + (size_t)row * DD + c8 * 8)
                                  : (b + (size_t)(row - BQ) * DD + c8 * 8);
    float4 v0 = reinterpret_cast<const float4*>(src)[0];
    float4 v1 = reinterpret_cast<const float4*>(src)[1];
    bf16x8 res;
    res[0] = (short)f2bf(v0.x * SQS); res[1] = (short)f2bf(v0.y * SQS);
    res[2] = (short)f2bf(v0.z * SQS); res[3] = (short)f2bf(v0.w * SQS);
    res[4] = (short)f2bf(v1.x * SQS); res[5] = (short)f2bf(v1.y * SQS);
    res[6] = (short)f2bf(v1.z * SQS); res[7] = (short)f2bf(v1.w * SQS);
    int frag = ((row >> 4) * 4 + (c8 >> 2)) * 64 + (c8 & 3) * 16 + (row & 15);
    *reinterpret_cast<bf16x8*>(obF + (size_t)frag * 8) = res;

    if (t < N2) {
        // excl(i,j) == (key[i]==key[j]) covers BOTH the pair mask and the
        // target mask (rowmod==colmod implies identical target).
        int tv = tgt[t & (BQ - 1)];
        key[t] = (tv == -1) ? (0x40000000 + (t & (BQ - 1))) : tv;
    }
}

// ---- kernel 2: fused Gram + exp + mask + row sums --------------------------
// grid 512 = 64 row-tiles x 8 chunks; 512 thr = 8 waves (4wr x 2wc).
// A frags hoisted in registers; B double-buffered in LDS via global_load_lds.
__global__ __launch_bounds__(512, 4) void simloss_main(
        const ushort* __restrict__ obF, const int* __restrict__ key,
        float* __restrict__ pf, float* __restrict__ png)
{
    __shared__ ushort bpan[2][16384];    // 2 x 32KB B tile (fragment order)
    __shared__ int    kds[1024];         // chunk's column keys
    __shared__ float  rred[2][128][2];   // row partials across wc

    const int tid  = threadIdx.x;
    const int lane = tid & 63;
    const int wid  = tid >> 6;
    const int wr   = wid >> 1;           // 0..3
    const int wc   = wid & 1;            // 0..1
    const int l15  = lane & 15;
    const int l4   = lane >> 4;

    // XCD swizzle: 512 blocks, ch == XCD -> each XCD reads one B chunk + A
    const int raw = blockIdx.x;
    const int bid = (raw & 7) * 64 + (raw >> 3);
    const int ch  = bid >> 6;            // 0..7
    const int rt  = bid & 63;            // 0..63
    const int rowbase = rt * 128;

    const bf16x8* F = reinterpret_cast<const bf16x8*>(obF);
    const char* gB = (const char*)obF + (size_t)ch * 262144;  // chunk's B cols

    // prologue: stage buf0 (ct=0) and the chunk's keys
    {
        unsigned lb = (unsigned)__builtin_amdgcn_readfirstlane(wid * 1024);
        const char* g = gB + tid * 16;
#pragma unroll
        for (int r = 0; r < 4; ++r)
            gll(g + r * 8192, (char*)&bpan[0][0] + lb + r * 8192);
        if (wid < 4)
            gll((const char*)(key + ch * 1024) + tid * 16, (char*)&kds[0] + lb);
    }

    // A fragments for this block's 128 rows (wave wr: rows wr*32..wr*32+32)
    bf16x8 af[2][4];
#pragma unroll
    for (int m = 0; m < 2; ++m)
#pragma unroll
        for (int kk = 0; kk < 4; ++kk)
            af[m][kk] = F[((rt * 8 + wr * 2 + m) * 4 + kk) * 64 + lane];

    int rk[2][4];
#pragma unroll
    for (int m = 0; m < 2; ++m)
#pragma unroll
        for (int r = 0; r < 4; ++r)
            rk[m][r] = key[rowbase + wr * 32 + m * 16 + l4 * 4 + r];

    __syncthreads();   // vmcnt(0) drain -> buf0 + kds ready

    float fs[2][4] = {}, ns[2][4] = {};
    const unsigned bbase = (unsigned)(wc * 16384 + lane * 16);
    const unsigned kbase = (unsigned)(wc * 256 + l15 * 4);

#pragma unroll
    for (int ct = 0; ct < NCT; ++ct) {
        const int buf = ct & 1;
        // issue next tile's staging first; lands during this ct's compute
        if (ct + 1 < NCT) {
            unsigned lb = (unsigned)__builtin_amdgcn_readfirstlane(
                (((ct + 1) & 1) << 15) + wid * 1024);
            const char* g = gB + (ct + 1) * 32768 + tid * 16;
#pragma unroll
            for (int r = 0; r < 4; ++r)
                gll(g + r * 8192, (char*)&bpan[0][0] + lb + r * 8192);
        }

        int ck[4];
#pragma unroll
        for (int n = 0; n < 4; ++n)
            ck[n] = *(const int*)((const char*)kds + (kbase + ct * 512 + n * 64));

        f32x4 acc[2][4] = {};
#pragma unroll
        for (int kk = 0; kk < 4; ++kk) {
            bf16x8 bf[4];
#pragma unroll
            for (int n = 0; n < 4; ++n)
                bf[n] = *reinterpret_cast<const bf16x8*>(
                    (const char*)&bpan[0][0] + (buf * 32768 + bbase + (n * 4 + kk) * 1024));
#pragma unroll
            for (int m = 0; m < 2; ++m)
#pragma unroll
                for (int n = 0; n < 4; ++n)
                    acc[m][n] = __builtin_amdgcn_mfma_f32_16x16x32_bf16(
                        af[m][kk], bf[n], acc[m][n], 0, 0, 0);
        }

        // epilogue: exp2 directly (inputs pre-scaled); single-compare mask
#pragma unroll
        for (int m = 0; m < 2; ++m)
#pragma unroll
            for (int n = 0; n < 4; ++n)
#pragma unroll
                for (int r = 0; r < 4; ++r) {
                    float e = __builtin_amdgcn_exp2f(acc[m][n][r]);
                    fs[m][r] += e;
                    ns[m][r] += (rk[m][r] == ck[n]) ? 0.0f : e;
                }

        __syncthreads();   // buf consumed by all; next stage may overwrite
    }

    // reduce across the 16 column-lanes, combine wc halves via LDS
#pragma unroll
    for (int m = 0; m < 2; ++m)
#pragma unroll
        for (int r = 0; r < 4; ++r) {
            float f = fs[m][r], g = ns[m][r];
#pragma unroll
            for (int msk = 1; msk < 16; msk <<= 1) {
                f += __shfl_xor(f, msk);
                g += __shfl_xor(g, msk);
            }
            if (l15 == 0) {
                int rl = wr * 32 + m * 16 + l4 * 4 + r;
                rred[wc][rl][0] = f;
                rred[wc][rl][1] = g;
            }
        }
    __syncthreads();
    if (tid < 128) {
        float f = rred[0][tid][0] + rred[1][tid][0];
        float g = rred[0][tid][1] + rred[1][tid][1];
        pf [ch * N2 + rowbase + tid] = f;
        png[ch * N2 + rowbase + tid] = g;
    }
}

// ---- kernel 3: per-row loss + block partial -------------------------------
__global__ __launch_bounds__(256) void row_loss_k(
        const float* __restrict__ pf, const float* __restrict__ png,
        float* __restrict__ bpart)
{
    int row = blockIdx.x * 256 + threadIdx.x;
    float full = 0.f, ng = 0.f;
#pragma unroll
    for (int s = 0; s < NCHK; ++s) {
        full += pf[s * N2 + row];
        ng   += png[s * N2 + row];
    }
    float o1 = full - 0.9f * ng;                // (1 - tau+) = 0.9
    float o2 = full + 818.1f * ng;              // n*tau+ - (1-tau+) = 819 - 0.9
    float li = (__builtin_amdgcn_logf(o2) - __builtin_amdgcn_logf(o1)) * 0.6931471805599453f;

#pragma unroll
    for (int m = 1; m < 64; m <<= 1) li += __shfl_xor(li, m);
    __shared__ float red[4];
    if ((threadIdx.x & 63) == 0) red[threadIdx.x >> 6] = li;
    __syncthreads();
    if (threadIdx.x == 0) bpart[blockIdx.x] = red[0] + red[1] + red[2] + red[3];
}

// ---- kernel 4: final scalar ----------------------------------------------
__global__ void final_k(const float* __restrict__ bpart, float* __restrict__ out)
{
    int l = threadIdx.x;
    float v = (l < 32) ? bpart[l] : 0.f;
#pragma unroll
    for (int m = 1; m < 32; m <<= 1) v += __shfl_xor(v, m);
    if (l == 0) out[0] = v / (float)N2;
}

extern "C" void kernel_launch(void* const* d_in, const int* in_sizes, int n_in,
                              void* d_out, int out_size, void* d_ws, size_t ws_size,
                              hipStream_t stream)
{
    const float* out1 = (const float*)d_in[0];
    const float* out2 = (const float*)d_in[1];
    // d_in[2] = out_m, unused by the loss math
    const int*   tgt  = (const int*)d_in[3];
    float* out = (float*)d_out;

    // ws: obF 2MB | pf 256KB | png 256KB | key 32KB | bpart
    ushort* obF  = (ushort*)d_ws;
    float*  pf   = (float*)((char*)d_ws + (2u << 20));
    float*  png  = (float*)((char*)d_ws + (2u << 20) + 262144);
    int*    key  = (int*)  ((char*)d_ws + (2u << 20) + 524288);
    float*  bpart= (float*)((char*)d_ws + (2u << 20) + 524288 + 32768);

    convert_k<<<(N2 * DD / 8) / 256, 256, 0, stream>>>(out1, out2, tgt, obF, key);
    simloss_main<<<512, 512, 0, stream>>>(obF, key, pf, png);
    row_loss_k<<<N2 / 256, 256, 0, stream>>>(pf, png, bpart);
    final_k<<<1, 64, 0, stream>>>(bpart, out);
}

// Round 5
// 39.519 us; speedup vs baseline: 6.0454x; 6.0454x over previous
//
#include <hip/hip_runtime.h>
#include <hip/hip_bf16.h>

typedef __attribute__((ext_vector_type(8))) short bf16x8;
typedef __attribute__((ext_vector_type(4))) float f32x4;

constexpr int BQ  = 4096;          // batch per view
constexpr int DD  = 128;           // dim
constexpr int N2  = 2 * BQ;        // 8192
constexpr int NCHK = 8;            // column chunks (1024 cols each)
constexpr int NCT  = 8;            // 128-col tiles per chunk
// exp(s/T) = exp2(s * 2/ln2); pre-scale matrix by sqrt(2.8853900817779268)
constexpr float SQS = 1.6986433f;

static __device__ __forceinline__ ushort f2bf(float f) {
    unsigned u = __builtin_bit_cast(unsigned, f);
    u += 0x7FFFu + ((u >> 16) & 1u);     // round-to-nearest-even
    return (ushort)(u >> 16);
}

static __device__ __forceinline__ void gll(const void* g, void* l) {
    __builtin_amdgcn_global_load_lds(
        (const __attribute__((address_space(1))) void*)g,
        (__attribute__((address_space(3))) void*)l, 16, 0, 0);
}

// ---- kernel 1: fp32 -> bf16 in MFMA-fragment order, plus mask keys --------
// obF layout: frag(group,kk) at index (group*4+kk)*64+lane, 8 bf16 per lane:
// a fragment load is F[base+lane] -> one fully contiguous 1KB load per wave.
__global__ __launch_bounds__(256) void convert_k(const float* __restrict__ a,
        const float* __restrict__ b, const int* __restrict__ tgt,
        ushort* __restrict__ obF, int* __restrict__ key)
{
    int t = blockIdx.x * 256 + threadIdx.x;          // 131072 threads
    int row = t >> 4, c8 = t & 15;
    const float* src = (row < BQ) ? (a + (size_t)row * DD + c8 * 8)
                                  : (b + (size_t)(row - BQ) * DD + c8 * 8);
    float4 v0 = reinterpret_cast<const float4*>(src)[0];
    float4 v1 = reinterpret_cast<const float4*>(src)[1];
    bf16x8 res;
    res[0] = (short)f2bf(v0.x * SQS); res[1] = (short)f2bf(v0.y * SQS);
    res[2] = (short)f2bf(v0.z * SQS); res[3] = (short)f2bf(v0.w * SQS);
    res[4] = (short)f2bf(v1.x * SQS); res[5] = (short)f2bf(v1.y * SQS);
    res[6] = (short)f2bf(v1.z * SQS); res[7] = (short)f2bf(v1.w * SQS);
    int frag = ((row >> 4) * 4 + (c8 >> 2)) * 64 + (c8 & 3) * 16 + (row & 15);
    *reinterpret_cast<bf16x8*>(obF + (size_t)frag * 8) = res;

    if (t < N2) {
        // excl(i,j) == (key[i]==key[j]) covers BOTH the pair mask and the
        // target mask (rowmod==colmod implies identical target).
        int tv = tgt[t & (BQ - 1)];
        key[t] = (tv == -1) ? (0x40000000 + (t & (BQ - 1))) : tv;
    }
}

// ---- kernel 2: fused Gram + exp + mask + row sums --------------------------
// grid 512 = 64 row-tiles x 8 chunks; 512 thr = 8 waves (4wr x 2wc).
// A frags hoisted; B double-buffered in LDS via global_load_lds; ROLLED loop.
__global__ __launch_bounds__(512, 2) void simloss_main(
        const ushort* __restrict__ obF, const int* __restrict__ key,
        float* __restrict__ pf, float* __restrict__ png)
{
    __shared__ ushort bpan[2][16384];    // 2 x 32KB B tile (fragment order)
    __shared__ int    kds[1024];         // chunk's column keys
    __shared__ float  rred[2][128][2];   // row partials across wc

    const int tid  = threadIdx.x;
    const int lane = tid & 63;
    const int wid  = tid >> 6;
    const int wr   = wid >> 1;           // 0..3
    const int wc   = wid & 1;            // 0..1
    const int l15  = lane & 15;
    const int l4   = lane >> 4;

    // XCD swizzle: 512 blocks, ch == XCD -> each XCD reads one B chunk + A
    const int raw = blockIdx.x;
    const int bid = (raw & 7) * 64 + (raw >> 3);
    const int ch  = bid >> 6;            // 0..7
    const int rt  = bid & 63;            // 0..63
    const int rowbase = rt * 128;

    const bf16x8* F = reinterpret_cast<const bf16x8*>(obF);
    const char* gB = (const char*)obF + (size_t)ch * 262144;  // chunk's B cols
    char* lbase = (char*)&bpan[0][0];

    // prologue: stage buf0 (ct=0) and the chunk's keys
    {
        unsigned lb = (unsigned)__builtin_amdgcn_readfirstlane(wid * 1024);
        const char* g = gB + tid * 16;
#pragma unroll
        for (int r = 0; r < 4; ++r)
            gll(g + r * 8192, lbase + lb + r * 8192);
        if (wid < 4)
            gll((const char*)(key + ch * 1024) + tid * 16, (char*)&kds[0] + lb);
    }

    // A fragments for this block's 128 rows (wave wr: rows wr*32..wr*32+32)
    bf16x8 af[2][4];
#pragma unroll
    for (int m = 0; m < 2; ++m)
#pragma unroll
        for (int kk = 0; kk < 4; ++kk)
            af[m][kk] = F[((rt * 8 + wr * 2 + m) * 4 + kk) * 64 + lane];

    int rk[2][4];
#pragma unroll
    for (int m = 0; m < 2; ++m)
#pragma unroll
        for (int r = 0; r < 4; ++r)
            rk[m][r] = key[rowbase + wr * 32 + m * 16 + l4 * 4 + r];

    __syncthreads();   // vmcnt(0) drain -> buf0 + kds ready

    float fs[2][4] = {}, ns[2][4] = {};
    const unsigned bbase = (unsigned)(wc * 16384 + lane * 16);
    const int kcol = wc * 64 + l15;

    const char* gnext = gB + 32768 + tid * 16;   // next tile's global src
    unsigned stageLds = 32768 + wid * 1024;       // buf1 first

#pragma unroll 1
    for (int ct = 0; ct < NCT; ++ct) {
        // issue next tile's staging first; lands during this ct's compute
        if (ct < NCT - 1) {
            unsigned lb = (unsigned)__builtin_amdgcn_readfirstlane(stageLds);
#pragma unroll
            for (int r = 0; r < 4; ++r)
                gll(gnext + r * 8192, lbase + lb + r * 8192);
            gnext += 32768;
            stageLds ^= 32768;
        }

        int ck[4];
#pragma unroll
        for (int n = 0; n < 4; ++n)
            ck[n] = kds[ct * 128 + kcol + n * 16];

        const char* bufp = lbase + ((ct & 1) << 15);
        f32x4 acc[2][4] = {};
#pragma unroll
        for (int kk = 0; kk < 4; ++kk) {
            bf16x8 bf[4];
#pragma unroll
            for (int n = 0; n < 4; ++n)
                bf[n] = *reinterpret_cast<const bf16x8*>(
                    bufp + bbase + (unsigned)((n * 4 + kk) * 1024));
#pragma unroll
            for (int m = 0; m < 2; ++m)
#pragma unroll
                for (int n = 0; n < 4; ++n)
                    acc[m][n] = __builtin_amdgcn_mfma_f32_16x16x32_bf16(
                        af[m][kk], bf[n], acc[m][n], 0, 0, 0);
        }

        // epilogue: exp2 directly (inputs pre-scaled); single-compare mask
#pragma unroll
        for (int m = 0; m < 2; ++m)
#pragma unroll
            for (int n = 0; n < 4; ++n)
#pragma unroll
                for (int r = 0; r < 4; ++r) {
                    float e = __builtin_amdgcn_exp2f(acc[m][n][r]);
                    fs[m][r] += e;
                    ns[m][r] += (rk[m][r] == ck[n]) ? 0.0f : e;
                }

        __syncthreads();   // buf consumed by all; next stage may overwrite
    }

    // reduce across the 16 column-lanes, combine wc halves via LDS
#pragma unroll
    for (int m = 0; m < 2; ++m)
#pragma unroll
        for (int r = 0; r < 4; ++r) {
            float f = fs[m][r], g = ns[m][r];
#pragma unroll
            for (int msk = 1; msk < 16; msk <<= 1) {
                f += __shfl_xor(f, msk);
                g += __shfl_xor(g, msk);
            }
            if (l15 == 0) {
                int rl = wr * 32 + m * 16 + l4 * 4 + r;
                rred[wc][rl][0] = f;
                rred[wc][rl][1] = g;
            }
        }
    __syncthreads();
    if (tid < 128) {
        float f = rred[0][tid][0] + rred[1][tid][0];
        float g = rred[0][tid][1] + rred[1][tid][1];
        pf [ch * N2 + rowbase + tid] = f;
        png[ch * N2 + rowbase + tid] = g;
    }
}

// ---- kernel 3: per-row loss + block partial -------------------------------
__global__ __launch_bounds__(256) void row_loss_k(
        const float* __restrict__ pf, const float* __restrict__ png,
        float* __restrict__ bpart)
{
    int row = blockIdx.x * 256 + threadIdx.x;
    float full = 0.f, ng = 0.f;
#pragma unroll
    for (int s = 0; s < NCHK; ++s) {
        full += pf[s * N2 + row];
        ng   += png[s * N2 + row];
    }
    float o1 = full - 0.9f * ng;                // (1 - tau+) = 0.9
    float o2 = full + 818.1f * ng;              // n*tau+ - (1-tau+) = 819 - 0.9
    float li = (__builtin_amdgcn_logf(o2) - __builtin_amdgcn_logf(o1)) * 0.6931471805599453f;

#pragma unroll
    for (int m = 1; m < 64; m <<= 1) li += __shfl_xor(li, m);
    __shared__ float red[4];
    if ((threadIdx.x & 63) == 0) red[threadIdx.x >> 6] = li;
    __syncthreads();
    if (threadIdx.x == 0) bpart[blockIdx.x] = red[0] + red[1] + red[2] + red[3];
}

// ---- kernel 4: final scalar ----------------------------------------------
__global__ void final_k(const float* __restrict__ bpart, float* __restrict__ out)
{
    int l = threadIdx.x;
    float v = (l < 32) ? bpart[l] : 0.f;
#pragma unroll
    for (int m = 1; m < 32; m <<= 1) v += __shfl_xor(v, m);
    if (l == 0) out[0] = v / (float)N2;
}

extern "C" void kernel_launch(void* const* d_in, const int* in_sizes, int n_in,
                              void* d_out, int out_size, void* d_ws, size_t ws_size,
                              hipStream_t stream)
{
    const float* out1 = (const float*)d_in[0];
    const float* out2 = (const float*)d_in[1];
    // d_in[2] = out_m, unused by the loss math
    const int*   tgt  = (const int*)d_in[3];
    float* out = (float*)d_out;

    // ws: obF 2MB | pf 256KB | png 256KB | key 32KB | bpart
    ushort* obF  = (ushort*)d_ws;
    float*  pf   = (float*)((char*)d_ws + (2u << 20));
    float*  png  = (float*)((char*)d_ws + (2u << 20) + 262144);
    int*    key  = (int*)  ((char*)d_ws + (2u << 20) + 524288);
    float*  bpart= (float*)((char*)d_ws + (2u << 20) + 524288 + 32768);

    convert_k<<<(N2 * DD / 8) / 256, 256, 0, stream>>>(out1, out2, tgt, obF, key);
    simloss_main<<<512, 512, 0, stream>>>(obF, key, pf, png);
    row_loss_k<<<N2 / 256, 256, 0, stream>>>(pf, png, bpart);
    final_k<<<1, 64, 0, stream>>>(bpart, out);
}